// Round 1
// baseline (82.545 us; speedup 1.0000x reference)
//
#include <hip/hip_runtime.h>
#include <math.h>

#define NB   1024
#define CH   60
#define SW   288
#define F1C  8
#define FD   16   // F1*D
#define F2C  16
#define KLEN 64
#define NCLS 4
#define PWID 72
#define NV   9
#define FEAT 144

#define XR_STRIDE 353   // 352 padded cols + 1 (bank spread)
#define PH_STRIDE 73
#define W1_STRIDE 65

__device__ __forceinline__ float elu1(float v) {
    return v > 0.f ? v : expm1f(v);
}

__global__ __launch_bounds__(256, 4) void eegnet_main(
    const float* __restrict__ x, const int* __restrict__ y,
    const float* __restrict__ conv1_w,
    const float* __restrict__ bn1_g, const float* __restrict__ bn1_b,
    const float* __restrict__ bn1_m, const float* __restrict__ bn1_v,
    const float* __restrict__ dw_w,
    const float* __restrict__ bn2_g, const float* __restrict__ bn2_b,
    const float* __restrict__ bn2_m, const float* __restrict__ bn2_v,
    const float* __restrict__ pw_w,
    const float* __restrict__ bn3_g, const float* __restrict__ bn3_b,
    const float* __restrict__ bn3_m, const float* __restrict__ bn3_v,
    const float* __restrict__ fc_w, const float* __restrict__ fc_b,
    float* __restrict__ probs_out, float* __restrict__ feat_out,
    float* __restrict__ sums_out)
{
    __shared__ float s_xr[FD * XR_STRIDE];   // channel-reduced, width-padded signal
    __shared__ float s_ph[FD * PH_STRIDE];   // after conv+bn2+elu+pool4
    __shared__ float s_w1[F1C * W1_STRIDE];  // conv1 taps, stride 65 (bank spread)
    __shared__ float s_dwf[FD * CH];         // depthwise weights [f][ch]
    __shared__ float s_pwT[FD * F2C];        // pointwise, transposed [f][f2]
    __shared__ float s_fc[NCLS * FEAT];
    __shared__ float s_feat[FEAT];
    __shared__ float s_A[FD], s_Cb[FD], s_a3[F2C], s_c3[F2C];

    const int tid = threadIdx.x;
    const int b = blockIdx.x;

    // ---- phase 0: stage weights, zero xr padding ----
    for (int i = tid; i < F1C * KLEN; i += 256)
        s_w1[(i >> 6) * W1_STRIDE + (i & 63)] = conv1_w[i];
    for (int i = tid; i < FD * CH; i += 256) s_dwf[i] = dw_w[i];
    for (int i = tid; i < F2C * FD; i += 256)
        s_pwT[(i & 15) * F2C + (i >> 4)] = pw_w[i];
    for (int i = tid; i < NCLS * FEAT; i += 256) s_fc[i] = fc_w[i];
    for (int i = tid; i < FD * 65; i += 256) {      // pads: [0,32) and [320,353)
        int f = i / 65, p = i % 65;
        int wp = (p < 32) ? p : (288 + p);
        s_xr[f * XR_STRIDE + wp] = 0.f;
    }
    __syncthreads();

    // ---- derived BN-folded params ----
    if (tid < FD) {
        const int f = tid, f1 = f >> 1;
        const float inv1 = bn1_g[f1] / sqrtf(bn1_v[f1] + 1e-3f);
        const float c1 = bn1_b[f1] - bn1_m[f1] * inv1;
        const float inv2 = bn2_g[f] / sqrtf(bn2_v[f] + 1e-3f);
        const float c2 = bn2_b[f] - bn2_m[f] * inv2;
        float sdw = 0.f;
        for (int ch = 0; ch < CH; ++ch) sdw += s_dwf[f * CH + ch];
        s_A[f] = inv2 * inv1;
        s_Cb[f] = inv2 * c1 * sdw + c2;
        const float inv3 = bn3_g[f] / sqrtf(bn3_v[f] + 1e-3f);
        s_a3[f] = inv3;
        s_c3[f] = bn3_b[f] - bn3_m[f] * inv3;
    }

    // ---- phase 1: channel reduction xr[f][w] = sum_ch dwf[f][ch]*x[b][ch][w] ----
    const float* xb = x + (size_t)b * (CH * SW);
    for (int w = tid; w < SW; w += 256) {
        float acc[FD];
        #pragma unroll
        for (int f = 0; f < FD; ++f) acc[f] = 0.f;
        #pragma unroll 4
        for (int ch = 0; ch < CH; ++ch) {
            const float v = xb[ch * SW + w];
            #pragma unroll
            for (int f = 0; f < FD; ++f)
                acc[f] = fmaf(s_dwf[f * CH + ch], v, acc[f]);
        }
        #pragma unroll
        for (int f = 0; f < FD; ++f) s_xr[f * XR_STRIDE + 32 + w] = acc[f];
    }
    __syncthreads();

    // ---- phase 2: width conv (K=64) + bn2 + elu + pool4 -> s_ph[f][u] ----
    for (int idx = tid; idx < FD * PWID; idx += 256) {
        const int f = idx & 15;        // f fastest: xr conflicts capped at 4-way
        const int u = idx >> 4;
        const float* xrp = &s_xr[f * XR_STRIDE + 4 * u];
        const float* w1p = &s_w1[(f >> 1) * W1_STRIDE];
        float x0 = xrp[0], x1 = xrp[1], x2 = xrp[2];
        float a0 = 0.f, a1 = 0.f, a2 = 0.f, a3 = 0.f;
        #pragma unroll
        for (int k = 0; k < KLEN; ++k) {    // sliding register ring: 2 LDS reads / 4 FMA
            const float x3 = xrp[k + 3];
            const float wv = w1p[k];
            a0 = fmaf(wv, x0, a0);
            a1 = fmaf(wv, x1, a1);
            a2 = fmaf(wv, x2, a2);
            a3 = fmaf(wv, x3, a3);
            x0 = x1; x1 = x2; x2 = x3;
        }
        const float Af = s_A[f], Cf = s_Cb[f];
        const float e0 = elu1(fmaf(Af, a0, Cf));
        const float e1 = elu1(fmaf(Af, a1, Cf));
        const float e2 = elu1(fmaf(Af, a2, Cf));
        const float e3 = elu1(fmaf(Af, a3, Cf));
        s_ph[f * PH_STRIDE + u] = (e0 + e1 + e2 + e3) * 0.25f;
    }
    __syncthreads();

    // ---- phase 3: pointwise 16x16 + bn3 + elu + pool8 -> feat[144] ----
    if (tid < FEAT) {
        const int f2 = tid / NV;
        const int v = tid - f2 * NV;
        const float a3f = s_a3[f2], c3f = s_c3[f2];
        float acc = 0.f;
        #pragma unroll
        for (int u8 = 0; u8 < 8; ++u8) {
            const int u = v * 8 + u8;
            float s = 0.f;
            #pragma unroll
            for (int f = 0; f < FD; ++f)
                s = fmaf(s_pwT[f * F2C + f2], s_ph[f * PH_STRIDE + u], s);
            acc += elu1(fmaf(a3f, s, c3f));
        }
        const float ft = acc * 0.125f;
        s_feat[tid] = ft;
        feat_out[(size_t)b * FEAT + tid] = ft;
        atomicAdd(&sums_out[y[b] * FEAT + tid], ft);
    }
    __syncthreads();

    // ---- phase 4: logits + softmax (wave 0) ----
    if (tid < 64) {
        float lg0 = 0.f, lg1 = 0.f, lg2 = 0.f, lg3 = 0.f;
        for (int j = tid; j < FEAT; j += 64) {
            const float fv = s_feat[j];
            lg0 = fmaf(fv, s_fc[0 * FEAT + j], lg0);
            lg1 = fmaf(fv, s_fc[1 * FEAT + j], lg1);
            lg2 = fmaf(fv, s_fc[2 * FEAT + j], lg2);
            lg3 = fmaf(fv, s_fc[3 * FEAT + j], lg3);
        }
        #pragma unroll
        for (int off = 32; off > 0; off >>= 1) {
            lg0 += __shfl_down(lg0, off, 64);
            lg1 += __shfl_down(lg1, off, 64);
            lg2 += __shfl_down(lg2, off, 64);
            lg3 += __shfl_down(lg3, off, 64);
        }
        if (tid == 0) {
            lg0 += fc_b[0]; lg1 += fc_b[1]; lg2 += fc_b[2]; lg3 += fc_b[3];
            const float m = fmaxf(fmaxf(lg0, lg1), fmaxf(lg2, lg3));
            const float e0 = expf(lg0 - m), e1 = expf(lg1 - m);
            const float e2 = expf(lg2 - m), e3 = expf(lg3 - m);
            const float inv = 1.f / (e0 + e1 + e2 + e3);
            float* po = probs_out + (size_t)b * NCLS;
            po[0] = e0 * inv; po[1] = e1 * inv; po[2] = e2 * inv; po[3] = e3 * inv;
        }
    }
}

__global__ __launch_bounds__(1024) void eegnet_centroid(
    const float* __restrict__ feat, const int* __restrict__ y,
    const float* __restrict__ sums, float* __restrict__ cl_out)
{
    __shared__ float s_cent[NCLS * FEAT];
    __shared__ int s_cnt[NCLS];
    __shared__ float s_red[16];
    const int tid = threadIdx.x;
    if (tid < NCLS) s_cnt[tid] = 0;
    __syncthreads();
    const int cls = y[tid];                 // exactly 1024 threads, one per sample
    atomicAdd(&s_cnt[cls], 1);
    __syncthreads();
    if (tid < NCLS * FEAT) {
        const int c = tid / FEAT;
        s_cent[tid] = sums[tid] / fmaxf((float)s_cnt[c], 1.0f);
    }
    __syncthreads();

    const float* fp = feat + (size_t)tid * FEAT;
    const float* cp = &s_cent[cls * FEAT];
    float acc = 0.f;
    #pragma unroll
    for (int j = 0; j < FEAT; j += 4) {
        const float4 fv = *reinterpret_cast<const float4*>(fp + j);
        float d;
        d = fv.x - cp[j + 0] + 1e-6f; acc = fmaf(d, d, acc);
        d = fv.y - cp[j + 1] + 1e-6f; acc = fmaf(d, d, acc);
        d = fv.z - cp[j + 2] + 1e-6f; acc = fmaf(d, d, acc);
        d = fv.w - cp[j + 3] + 1e-6f; acc = fmaf(d, d, acc);
    }
    float dist = sqrtf(acc);
    #pragma unroll
    for (int off = 32; off > 0; off >>= 1) dist += __shfl_down(dist, off, 64);
    if ((tid & 63) == 0) s_red[tid >> 6] = dist;
    __syncthreads();
    if (tid < 64) {
        float v = (tid < 16) ? s_red[tid] : 0.f;
        #pragma unroll
        for (int off = 8; off > 0; off >>= 1) v += __shfl_down(v, off, 64);
        if (tid == 0) cl_out[0] = v * (1.0f / 1024.0f);
    }
}

extern "C" void kernel_launch(void* const* d_in, const int* in_sizes, int n_in,
                              void* d_out, int out_size, void* d_ws, size_t ws_size,
                              hipStream_t stream) {
    const float* x       = (const float*)d_in[0];
    const int*   y       = (const int*)d_in[1];
    const float* conv1_w = (const float*)d_in[2];
    const float* bn1_g   = (const float*)d_in[3];
    const float* bn1_b   = (const float*)d_in[4];
    const float* bn1_m   = (const float*)d_in[5];
    const float* bn1_v   = (const float*)d_in[6];
    const float* dw_w    = (const float*)d_in[7];
    const float* bn2_g   = (const float*)d_in[8];
    const float* bn2_b   = (const float*)d_in[9];
    const float* bn2_m   = (const float*)d_in[10];
    const float* bn2_v   = (const float*)d_in[11];
    const float* pw_w    = (const float*)d_in[12];
    const float* bn3_g   = (const float*)d_in[13];
    const float* bn3_b   = (const float*)d_in[14];
    const float* bn3_m   = (const float*)d_in[15];
    const float* bn3_v   = (const float*)d_in[16];
    const float* fc_w    = (const float*)d_in[17];
    const float* fc_b    = (const float*)d_in[18];

    float* out   = (float*)d_out;
    float* probs = out;            // [1024*4]
    float* cl    = out + 4096;     // [1]
    float* sums  = (float*)d_ws;   // 576 floats (class sums)
    float* feat  = sums + 640;     // 1024*144 floats, 16B-aligned

    hipMemsetAsync(sums, 0, NCLS * FEAT * sizeof(float), stream);
    eegnet_main<<<NB, 256, 0, stream>>>(
        x, y, conv1_w, bn1_g, bn1_b, bn1_m, bn1_v,
        dw_w, bn2_g, bn2_b, bn2_m, bn2_v,
        pw_w, bn3_g, bn3_b, bn3_m, bn3_v,
        fc_w, fc_b, probs, feat, sums);
    eegnet_centroid<<<1, 1024, 0, stream>>>(feat, y, sums, cl);
}